// Round 2
// baseline (415.943 us; speedup 1.0000x reference)
//
#include <hip/hip_runtime.h>
#include <math.h>

#define BB 256
#define LL 512
#define DD 1024
#define NSPLIT 4          // doc split for gather kernels
#define TPB 128           // tokens per block = LL/NSPLIT

// ---------------------------------------------------------------------------
// Kernel 1: partial hidden sums. grid (NSPLIT, BB), block 256.
// Block (p,b) sums rows for tokens [p*128, p*128+128) over full D.
// ph[(b*NSPLIT+p)*DD + d] = sum of 128 rows (no 1/L yet).
// ---------------------------------------------------------------------------
__global__ __launch_bounds__(256) void k_hid_part(const int* __restrict__ tokens,
                                                  const float* __restrict__ emb,
                                                  float* __restrict__ ph) {
    __shared__ int toks[TPB];
    const int p   = blockIdx.x;
    const int b   = blockIdx.y;
    const int tid = threadIdx.x;

    if (tid < TPB) toks[tid] = tokens[b * LL + p * TPB + tid] + 1;
    __syncthreads();

    const int base_d = tid * 4;
    float4 acc = make_float4(0.f, 0.f, 0.f, 0.f);
    #pragma unroll 4
    for (int i = 0; i < TPB; ++i) {
        const int row = toks[i] * DD;
        const float4 e = *(const float4*)(emb + row + base_d);
        acc.x += e.x; acc.y += e.y; acc.z += e.z; acc.w += e.w;
    }
    *(float4*)(ph + (b * NSPLIT + p) * DD + base_d) = acc;
}

// ---------------------------------------------------------------------------
// Kernel 2: q[b,d] = sum_e W[d,e] * hidden[b,e], hidden = (sum of partials)/L.
// grid (D/64, B/4), block 256 (4 waves). 4 docs x 64 W-rows per block.
// ---------------------------------------------------------------------------
__global__ __launch_bounds__(256) void k_q(const float* __restrict__ ph,
                                           const float* __restrict__ W,
                                           float* __restrict__ q) {
    __shared__ float hs[4][DD];
    const int dt  = blockIdx.x;   // 0..15
    const int bt  = blockIdx.y;   // 0..63
    const int tid = threadIdx.x;

    #pragma unroll
    for (int j = 0; j < 4; ++j)
        #pragma unroll
        for (int k = 0; k < 4; ++k) {
            const int idx = k * 256 + tid;
            const int doc = bt * 4 + j;
            float s = 0.f;
            #pragma unroll
            for (int pp = 0; pp < NSPLIT; ++pp)
                s += ph[(doc * NSPLIT + pp) * DD + idx];
            hs[j][idx] = s * (1.0f / (float)LL);
        }
    __syncthreads();

    const int w = tid >> 6, lane = tid & 63;

    for (int i = 0; i < 16; ++i) {
        const int d = dt * 64 + w * 16 + i;
        float a0 = 0.f, a1 = 0.f, a2 = 0.f, a3 = 0.f;
        #pragma unroll
        for (int k = 0; k < 4; ++k) {
            const int off = k * 256 + lane * 4;
            const float4 wv = *(const float4*)(W + d * DD + off);
            const float4 h0 = *(const float4*)(&hs[0][off]);
            const float4 h1 = *(const float4*)(&hs[1][off]);
            const float4 h2 = *(const float4*)(&hs[2][off]);
            const float4 h3 = *(const float4*)(&hs[3][off]);
            a0 += wv.x * h0.x + wv.y * h0.y + wv.z * h0.z + wv.w * h0.w;
            a1 += wv.x * h1.x + wv.y * h1.y + wv.z * h1.z + wv.w * h1.w;
            a2 += wv.x * h2.x + wv.y * h2.y + wv.z * h2.z + wv.w * h2.w;
            a3 += wv.x * h3.x + wv.y * h3.y + wv.z * h3.z + wv.w * h3.w;
        }
        #pragma unroll
        for (int m = 32; m; m >>= 1) {
            a0 += __shfl_xor(a0, m, 64);
            a1 += __shfl_xor(a1, m, 64);
            a2 += __shfl_xor(a2, m, 64);
            a3 += __shfl_xor(a3, m, 64);
        }
        if (lane == 0) {
            q[(bt * 4 + 0) * DD + d] = a0;
            q[(bt * 4 + 1) * DD + d] = a1;
            q[(bt * 4 + 2) * DD + d] = a2;
            q[(bt * 4 + 3) * DD + d] = a3;
        }
    }
}

// ---------------------------------------------------------------------------
// Kernel 3: partial un-normalized softmax context.
// grid (NSPLIT, BB), block 256 (4 waves). Block (p,b) handles tokens
// [p*128, p*128+128); wave w owns 32 of them. NO running max (scores are
// ~N(0,2), |score| < 10 => exp is fp32-safe), so iterations are fully
// independent and the row loads pipeline.
// pct[(b*NSPLIT+p)*DD + d] = sum_l exp(score_l) * e_l[d]
// ps [b*NSPLIT+p]          = sum_l exp(score_l)
// ---------------------------------------------------------------------------
__global__ __launch_bounds__(256) void k_attn_part(const int* __restrict__ tokens,
                                                   const float* __restrict__ emb,
                                                   const float* __restrict__ q,
                                                   float* __restrict__ pct,
                                                   float* __restrict__ ps) {
    __shared__ int   toks[TPB];
    __shared__ float ctp[4][DD];
    __shared__ float sw[4];

    const int p   = blockIdx.x;
    const int b   = blockIdx.y;
    const int tid = threadIdx.x;
    if (tid < TPB) toks[tid] = tokens[b * LL + p * TPB + tid] + 1;
    __syncthreads();

    const int w = tid >> 6, lane = tid & 63;

    float4 q4[4];
    #pragma unroll
    for (int c = 0; c < 4; ++c)
        q4[c] = *(const float4*)(q + b * DD + c * 256 + lane * 4);

    float s = 0.f;
    float4 ct[4];
    #pragma unroll
    for (int c = 0; c < 4; ++c) ct[c] = make_float4(0.f, 0.f, 0.f, 0.f);

    #pragma unroll 2
    for (int i = 0; i < 32; ++i) {
        const int row = toks[w * 32 + i] * DD;
        float4 e4[4];
        #pragma unroll
        for (int c = 0; c < 4; ++c)
            e4[c] = *(const float4*)(emb + row + c * 256 + lane * 4);

        float pr = 0.f;
        #pragma unroll
        for (int c = 0; c < 4; ++c)
            pr += e4[c].x * q4[c].x + e4[c].y * q4[c].y +
                  e4[c].z * q4[c].z + e4[c].w * q4[c].w;
        #pragma unroll
        for (int mm = 32; mm; mm >>= 1) pr += __shfl_xor(pr, mm, 64);

        const float wexp = __expf(pr);
        s += wexp;
        #pragma unroll
        for (int c = 0; c < 4; ++c) {
            ct[c].x += wexp * e4[c].x;
            ct[c].y += wexp * e4[c].y;
            ct[c].z += wexp * e4[c].z;
            ct[c].w += wexp * e4[c].w;
        }
    }

    #pragma unroll
    for (int c = 0; c < 4; ++c)
        *(float4*)(&ctp[w][c * 256 + lane * 4]) = ct[c];
    if (lane == 0) sw[w] = s;
    __syncthreads();

    // merge 4 waves; thread tid finalizes dims [tid*4, tid*4+4)
    const int d = tid * 4;
    float4 a = make_float4(0.f, 0.f, 0.f, 0.f);
    #pragma unroll
    for (int j = 0; j < 4; ++j) {
        const float4 v = *(const float4*)(&ctp[j][d]);
        a.x += v.x; a.y += v.y; a.z += v.z; a.w += v.w;
    }
    *(float4*)(pct + (b * NSPLIT + p) * DD + d) = a;
    if (tid == 0) ps[b * NSPLIT + p] = sw[0] + sw[1] + sw[2] + sw[3];
}

// ---------------------------------------------------------------------------
// Kernel 4: final merge + normalize. grid BB, block 256.
// ---------------------------------------------------------------------------
__global__ __launch_bounds__(256) void k_final(const float* __restrict__ pct,
                                               const float* __restrict__ ps,
                                               float* __restrict__ out) {
    const int b   = blockIdx.x;
    const int tid = threadIdx.x;

    float denom = 0.f;
    #pragma unroll
    for (int pp = 0; pp < NSPLIT; ++pp) denom += ps[b * NSPLIT + pp];
    const float inv = 1.0f / denom;

    const int d = tid * 4;
    float4 a = make_float4(0.f, 0.f, 0.f, 0.f);
    #pragma unroll
    for (int pp = 0; pp < NSPLIT; ++pp) {
        const float4 v = *(const float4*)(pct + (b * NSPLIT + pp) * DD + d);
        a.x += v.x; a.y += v.y; a.z += v.z; a.w += v.w;
    }
    a.x *= inv; a.y *= inv; a.z *= inv; a.w *= inv;
    *(float4*)(out + b * DD + d) = a;
}

// ---------------------------------------------------------------------------
extern "C" void kernel_launch(void* const* d_in, const int* in_sizes, int n_in,
                              void* d_out, int out_size, void* d_ws, size_t ws_size,
                              hipStream_t stream) {
    const int*   tokens = (const int*)d_in[0];
    // d_in[1] = max_len (scalar), fixed to LL
    const float* emb    = (const float*)d_in[2];
    const float* W      = (const float*)d_in[3];
    float*       out    = (float*)d_out;

    float* ph  = (float*)d_ws;                    // BB*NSPLIT*DD = 4 MB
    float* q   = ph  + BB * NSPLIT * DD;          // BB*DD        = 1 MB
    float* pct = q   + BB * DD;                   // BB*NSPLIT*DD = 4 MB
    float* ps  = pct + BB * NSPLIT * DD;          // BB*NSPLIT    = 4 KB

    dim3 gpart(NSPLIT, BB);
    k_hid_part<<<gpart, 256, 0, stream>>>(tokens, emb, ph);
    dim3 g2(DD / 64, BB / 4);
    k_q<<<g2, 256, 0, stream>>>(ph, W, q);
    k_attn_part<<<gpart, 256, 0, stream>>>(tokens, emb, q, pct, ps);
    k_final<<<BB, 256, 0, stream>>>(pct, ps, out);
}

// Round 3
// 407.211 us; speedup vs baseline: 1.0214x; 1.0214x over previous
//
#include <hip/hip_runtime.h>
#include <math.h>
#include <stdint.h>

#define BB 256
#define LL 512
#define DD 1024
#define VV 50001          // table rows (V+1)
#define NSPLIT 8          // doc split for gather kernels
#define TPB (LL / NSPLIT) // 64 tokens per block

// ---- bf16 helpers (manual, RNE cast; shift/AND decode) ---------------------
__device__ __forceinline__ uint16_t f2bf(float x) {
    union { float f; uint32_t u; } v; v.f = x;
    const uint32_t r = (v.u + 0x7fffu + ((v.u >> 16) & 1u)) >> 16;
    return (uint16_t)r;
}
__device__ __forceinline__ float bf_lo(uint32_t u) {   // low 16 bits -> float
    union { uint32_t u; float f; } v; v.u = u << 16; return v.f;
}
__device__ __forceinline__ float bf_hi(uint32_t u) {   // high 16 bits -> float
    union { uint32_t u; float f; } v; v.u = u & 0xffff0000u; return v.f;
}

// ---------------------------------------------------------------------------
// Kernel 0: cast fp32 table -> bf16 table in workspace. Streaming, RNE.
// ---------------------------------------------------------------------------
__global__ __launch_bounds__(256) void k_cast(const float* __restrict__ src,
                                              uint16_t* __restrict__ dst,
                                              int n4) {
    int idx = blockIdx.x * 256 + threadIdx.x;
    const int stride = gridDim.x * 256;
    for (; idx < n4; idx += stride) {
        const float4 f = ((const float4*)src)[idx];
        ushort4 o;
        o.x = f2bf(f.x); o.y = f2bf(f.y); o.z = f2bf(f.z); o.w = f2bf(f.w);
        ((ushort4*)dst)[idx] = o;
    }
}

// ---------------------------------------------------------------------------
// Kernel 1: partial hidden sums over bf16 table. grid (NSPLIT, BB), block 256.
// Thread covers dims [tid*4, tid*4+4); 8 B (uint2 = 4 bf16) per row.
// Two independent accumulator chains for ILP.
// ---------------------------------------------------------------------------
__global__ __launch_bounds__(256) void k_hid_part(const int* __restrict__ tokens,
                                                  const uint16_t* __restrict__ embh,
                                                  float* __restrict__ ph) {
    __shared__ int toks[TPB];
    const int p = blockIdx.x, b = blockIdx.y, tid = threadIdx.x;
    if (tid < TPB) toks[tid] = tokens[b * LL + p * TPB + tid] + 1;
    __syncthreads();

    const int base_d = tid * 4;
    float4 a0 = make_float4(0.f, 0.f, 0.f, 0.f);
    float4 a1 = make_float4(0.f, 0.f, 0.f, 0.f);
    #pragma unroll 8
    for (int i = 0; i < TPB; i += 2) {
        const uint2 ua = *(const uint2*)(embh + toks[i]     * DD + base_d);
        const uint2 ub = *(const uint2*)(embh + toks[i + 1] * DD + base_d);
        a0.x += bf_lo(ua.x); a0.y += bf_hi(ua.x);
        a0.z += bf_lo(ua.y); a0.w += bf_hi(ua.y);
        a1.x += bf_lo(ub.x); a1.y += bf_hi(ub.x);
        a1.z += bf_lo(ub.y); a1.w += bf_hi(ub.y);
    }
    float4 o;
    o.x = a0.x + a1.x; o.y = a0.y + a1.y; o.z = a0.z + a1.z; o.w = a0.w + a1.w;
    *(float4*)(ph + (b * NSPLIT + p) * DD + base_d) = o;
}

// ---------------------------------------------------------------------------
// Kernel 2: q[b,d] = sum_e W[d,e] * hidden[b,e], hidden = (sum partials)/L.
// grid (D/64, B/8), block 256 (4 waves). 8 docs x 64 W-rows per block:
// each W row chunk loaded once, dotted against 8 LDS-resident hiddens.
// ---------------------------------------------------------------------------
__global__ __launch_bounds__(256) void k_q(const float* __restrict__ ph,
                                           const float* __restrict__ W,
                                           float* __restrict__ q) {
    __shared__ float hs[8][DD];   // 32 KB
    const int dt  = blockIdx.x;   // 0..15
    const int bt  = blockIdx.y;   // 0..31
    const int tid = threadIdx.x;

    #pragma unroll
    for (int j = 0; j < 8; ++j)
        #pragma unroll
        for (int k = 0; k < 4; ++k) {
            const int idx = k * 256 + tid;
            const int doc = bt * 8 + j;
            float s = 0.f;
            #pragma unroll
            for (int pp = 0; pp < NSPLIT; ++pp)
                s += ph[(doc * NSPLIT + pp) * DD + idx];
            hs[j][idx] = s * (1.0f / (float)LL);
        }
    __syncthreads();

    const int w = tid >> 6, lane = tid & 63;

    for (int i = 0; i < 16; ++i) {
        const int d = dt * 64 + w * 16 + i;
        float a[8];
        #pragma unroll
        for (int j = 0; j < 8; ++j) a[j] = 0.f;
        #pragma unroll
        for (int k = 0; k < 4; ++k) {
            const int off = k * 256 + lane * 4;
            const float4 wv = *(const float4*)(W + d * DD + off);
            #pragma unroll
            for (int j = 0; j < 8; ++j) {
                const float4 h = *(const float4*)(&hs[j][off]);
                a[j] += wv.x * h.x + wv.y * h.y + wv.z * h.z + wv.w * h.w;
            }
        }
        #pragma unroll
        for (int m = 32; m; m >>= 1)
            #pragma unroll
            for (int j = 0; j < 8; ++j) a[j] += __shfl_xor(a[j], m, 64);
        if (lane == 0) {
            #pragma unroll
            for (int j = 0; j < 8; ++j) q[(bt * 8 + j) * DD + d] = a[j];
        }
    }
}

// ---------------------------------------------------------------------------
// Kernel 3: partial un-normalized softmax context over bf16 table.
// grid (NSPLIT, BB), block 256 (4 waves); wave w owns 16 tokens.
// Lane covers dims [lane*16, lane*16+16): two uint4 loads (16 bf16 = 32 B).
// No running max (scores ~N(0,2); exp is fp32-safe). Iterations independent.
// ---------------------------------------------------------------------------
__global__ __launch_bounds__(256) void k_attn_part(const int* __restrict__ tokens,
                                                   const uint16_t* __restrict__ embh,
                                                   const float* __restrict__ q,
                                                   float* __restrict__ pct,
                                                   float* __restrict__ ps) {
    __shared__ int   toks[TPB];
    __shared__ float ctp[4][DD];  // 16 KB
    __shared__ float sw[4];

    const int p = blockIdx.x, b = blockIdx.y, tid = threadIdx.x;
    if (tid < TPB) toks[tid] = tokens[b * LL + p * TPB + tid] + 1;
    __syncthreads();

    const int w = tid >> 6, lane = tid & 63;
    const int dbase = lane * 16;

    float qq[16];
    #pragma unroll
    for (int c = 0; c < 4; ++c) {
        const float4 v = *(const float4*)(q + b * DD + dbase + c * 4);
        qq[c * 4 + 0] = v.x; qq[c * 4 + 1] = v.y;
        qq[c * 4 + 2] = v.z; qq[c * 4 + 3] = v.w;
    }

    float s = 0.f;
    float ct[16];
    #pragma unroll
    for (int k = 0; k < 16; ++k) ct[k] = 0.f;

    #pragma unroll 2
    for (int i = 0; i < 16; ++i) {
        const int row = toks[w * 16 + i] * DD;
        const uint4 ua = *(const uint4*)(embh + row + dbase);
        const uint4 ub = *(const uint4*)(embh + row + dbase + 8);
        float e[16];
        e[0]  = bf_lo(ua.x); e[1]  = bf_hi(ua.x);
        e[2]  = bf_lo(ua.y); e[3]  = bf_hi(ua.y);
        e[4]  = bf_lo(ua.z); e[5]  = bf_hi(ua.z);
        e[6]  = bf_lo(ua.w); e[7]  = bf_hi(ua.w);
        e[8]  = bf_lo(ub.x); e[9]  = bf_hi(ub.x);
        e[10] = bf_lo(ub.y); e[11] = bf_hi(ub.y);
        e[12] = bf_lo(ub.z); e[13] = bf_hi(ub.z);
        e[14] = bf_lo(ub.w); e[15] = bf_hi(ub.w);

        float pr = 0.f;
        #pragma unroll
        for (int k = 0; k < 16; ++k) pr += e[k] * qq[k];
        #pragma unroll
        for (int mm = 32; mm; mm >>= 1) pr += __shfl_xor(pr, mm, 64);

        const float wexp = __expf(pr);
        s += wexp;
        #pragma unroll
        for (int k = 0; k < 16; ++k) ct[k] += wexp * e[k];
    }

    #pragma unroll
    for (int c = 0; c < 4; ++c) {
        float4 v;
        v.x = ct[c * 4 + 0]; v.y = ct[c * 4 + 1];
        v.z = ct[c * 4 + 2]; v.w = ct[c * 4 + 3];
        *(float4*)(&ctp[w][dbase + c * 4]) = v;
    }
    if (lane == 0) sw[w] = s;
    __syncthreads();

    const int d = tid * 4;
    float4 a = make_float4(0.f, 0.f, 0.f, 0.f);
    #pragma unroll
    for (int j = 0; j < 4; ++j) {
        const float4 v = *(const float4*)(&ctp[j][d]);
        a.x += v.x; a.y += v.y; a.z += v.z; a.w += v.w;
    }
    *(float4*)(pct + (b * NSPLIT + p) * DD + d) = a;
    if (tid == 0) ps[b * NSPLIT + p] = sw[0] + sw[1] + sw[2] + sw[3];
}

// ---------------------------------------------------------------------------
// Kernel 4: final merge + normalize. grid BB, block 256.
// ---------------------------------------------------------------------------
__global__ __launch_bounds__(256) void k_final(const float* __restrict__ pct,
                                               const float* __restrict__ ps,
                                               float* __restrict__ out) {
    const int b = blockIdx.x, tid = threadIdx.x;

    float denom = 0.f;
    #pragma unroll
    for (int pp = 0; pp < NSPLIT; ++pp) denom += ps[b * NSPLIT + pp];
    const float inv = 1.0f / denom;

    const int d = tid * 4;
    float4 a = make_float4(0.f, 0.f, 0.f, 0.f);
    #pragma unroll
    for (int pp = 0; pp < NSPLIT; ++pp) {
        const float4 v = *(const float4*)(pct + (b * NSPLIT + pp) * DD + d);
        a.x += v.x; a.y += v.y; a.z += v.z; a.w += v.w;
    }
    a.x *= inv; a.y *= inv; a.z *= inv; a.w *= inv;
    *(float4*)(out + b * DD + d) = a;
}

// ---------------------------------------------------------------------------
extern "C" void kernel_launch(void* const* d_in, const int* in_sizes, int n_in,
                              void* d_out, int out_size, void* d_ws, size_t ws_size,
                              hipStream_t stream) {
    const int*   tokens = (const int*)d_in[0];
    // d_in[1] = max_len (scalar), fixed to LL
    const float* emb    = (const float*)d_in[2];
    const float* W      = (const float*)d_in[3];
    float*       out    = (float*)d_out;

    // workspace layout (needs ~120 MB; ws is ~800 MB)
    uint16_t* embh = (uint16_t*)d_ws;                         // VV*DD bf16 = 102.4 MB
    float*    ph   = (float*)((char*)d_ws + (size_t)VV * DD * 2); // BB*NSPLIT*DD = 8 MB
    float*    q    = ph  + (size_t)BB * NSPLIT * DD;          // BB*DD = 1 MB
    float*    pct  = q   + (size_t)BB * DD;                   // BB*NSPLIT*DD = 8 MB
    float*    ps   = pct + (size_t)BB * NSPLIT * DD;          // BB*NSPLIT = 8 KB

    const int n4 = VV * DD / 4;   // 12,800,256 float4s
    k_cast<<<4096, 256, 0, stream>>>(emb, embh, n4);

    dim3 gpart(NSPLIT, BB);
    k_hid_part<<<gpart, 256, 0, stream>>>(tokens, embh, ph);
    dim3 g2(DD / 64, BB / 8);
    k_q<<<g2, 256, 0, stream>>>(ph, W, q);
    k_attn_part<<<gpart, 256, 0, stream>>>(tokens, embh, q, pct, ps);
    k_final<<<BB, 256, 0, stream>>>(pct, ps, out);
}